// Round 6
// baseline (1019.605 us; speedup 1.0000x reference)
//
#include <hip/hip_runtime.h>
#include <math.h>

#define B_   16
#define C_   512
#define C8_  64
#define HW_  4096
#define KW2_ 576   // C_ + C8_
#define EPS_ 1e-5f

// 16-output FMA microtile: accv[i] += rowptr[i] * sv, via 4x float4 broadcast reads
#define FMA16(accv, sv, rowptr) do {                                            \
    const float4* _w = (const float4*)(rowptr);                                 \
    float4 _w0 = _w[0], _w1 = _w[1], _w2 = _w[2], _w3 = _w[3];                  \
    float _s = (sv);                                                            \
    accv[0]  += _w0.x*_s; accv[1]  += _w0.y*_s; accv[2]  += _w0.z*_s; accv[3]  += _w0.w*_s; \
    accv[4]  += _w1.x*_s; accv[5]  += _w1.y*_s; accv[6]  += _w1.z*_s; accv[7]  += _w1.w*_s; \
    accv[8]  += _w2.x*_s; accv[9]  += _w2.y*_s; accv[10] += _w2.z*_s; accv[11] += _w2.w*_s; \
    accv[12] += _w3.x*_s; accv[13] += _w3.y*_s; accv[14] += _w3.z*_s; accv[15] += _w3.w*_s; \
} while (0)

// ---------------------------------------------------------------------------
// A: fused proj_key + partial energy.
// Each block owns a 256-wide n-chunk of one batch. For each 64-wide subchunk:
//   key[k,n] = key_b[k] + sum_c key_w[k,c]*x[b,c,n]   (computed in regs->LDS)
//   eacc[q,k] += sum_n key[k,n]*att[b,q,n]
// epart[b][ch][q][k]. grid (16, B), block (64,4).
// ---------------------------------------------------------------------------
__global__ __launch_bounds__(256) void k_key_energy(
        const float* __restrict__ x, const float* __restrict__ key_w,
        const float* __restrict__ key_b, const float* __restrict__ att,
        float* __restrict__ epart) {
    __shared__ __align__(16) float sA[64][65];   // x tile [c_local][n]
    __shared__ __align__(16) float sW[64][68];   // key_w tile [c_local][k]
    __shared__ __align__(16) float keyS[64][65]; // key tile [k][n_local]
    __shared__ __align__(16) float attT[64][68]; // att tile [n_local][q]
    const int tx = threadIdx.x, ty = threadIdx.y;
    const int ch = blockIdx.x, b = blockIdx.y;

    float eacc[16];
    #pragma unroll
    for (int i = 0; i < 16; ++i) eacc[i] = 0.f;

    for (int sc = 0; sc < 4; ++sc) {
        const int nb = ch * 256 + sc * 64;
        float kacc[16];
        #pragma unroll
        for (int i = 0; i < 16; ++i) kacc[i] = 0.f;

        for (int cc = 0; cc < 8; ++cc) {
            const int c0 = cc * 64;
            #pragma unroll
            for (int i = 0; i < 16; ++i) {
                const int r = ty * 16 + i;
                sA[r][tx] = x[((size_t)b * C_ + c0 + r) * HW_ + nb + tx];
                sW[tx][r] = key_w[(size_t)r * C_ + c0 + tx];
            }
            __syncthreads();
            #pragma unroll 4
            for (int jj = 0; jj < 64; ++jj)
                FMA16(kacc, sA[jj][tx], &sW[jj][ty * 16]);  // kacc[i]: k=ty*16+i, n=tx
            __syncthreads();
        }
        #pragma unroll
        for (int i = 0; i < 16; ++i) {
            const int r = ty * 16 + i;
            keyS[r][tx] = kacc[i] + key_b[r];
            attT[tx][r] = att[((size_t)b * C8_ + r) * HW_ + nb + tx];
        }
        __syncthreads();
        #pragma unroll 4
        for (int nn = 0; nn < 64; ++nn)
            FMA16(eacc, keyS[tx][nn], &attT[nn][ty * 16]); // eacc[j]: q=ty*16+j, k=tx
        __syncthreads();
    }
    #pragma unroll
    for (int j = 0; j < 16; ++j) {
        const int q = ty * 16 + j;
        epart[((size_t)(b * 16 + ch) * 64 + q) * 64 + tx] = eacc[j];
    }
}

// ---------------------------------------------------------------------------
// B: reduce partials -> energy, softmax over q (axis=-1), fold conv1+bn scale:
//    M[b][o][q] = s1[o] * sum_k c1_w[o,k] * attention[k,q]
// grid (B), block (64,4).
// ---------------------------------------------------------------------------
__global__ __launch_bounds__(256) void k_softmax_M(
        const float* __restrict__ epart, const float* __restrict__ c1_w,
        const float* __restrict__ c1_gamma, const float* __restrict__ c1_var,
        float* __restrict__ M) {
    __shared__ __align__(16) float eT[64][65];    // [q][k]
    __shared__ __align__(16) float attnS[64][65]; // [k][q]
    __shared__ __align__(16) float c1T[64][68];   // [k][o]
    const int tx = threadIdx.x, ty = threadIdx.y;
    const int t = ty * 64 + tx;
    const int b = blockIdx.x;

    for (int idx = t; idx < 4096; idx += 256) {
        float s = 0.f;
        #pragma unroll
        for (int ch = 0; ch < 16; ++ch)
            s += epart[(size_t)(b * 16 + ch) * 4096 + idx];
        eT[idx >> 6][idx & 63] = s;   // eT[q][k] = energy[b,k,q]
    }
    #pragma unroll
    for (int i = 0; i < 16; ++i) {
        const int oo = ty * 16 + i;
        c1T[tx][oo] = c1_w[oo * 64 + tx];
    }
    __syncthreads();

    if (t < 64) {           // one thread per k-row; softmax over q
        const int k = t;
        float m = -1e30f;
        for (int q = 0; q < 64; ++q) m = fmaxf(m, eT[q][k]);
        float s = 0.f;
        for (int q = 0; q < 64; ++q) {
            const float p = __expf(eT[q][k] - m);
            attnS[k][q] = p;
            s += p;
        }
        const float inv = 1.f / s;
        for (int q = 0; q < 64; ++q) attnS[k][q] *= inv;
    }
    __syncthreads();

    float acc[16];
    #pragma unroll
    for (int i = 0; i < 16; ++i) acc[i] = 0.f;
    #pragma unroll 4
    for (int k = 0; k < 64; ++k)
        FMA16(acc, attnS[k][tx], &c1T[k][ty * 16]);  // acc[i]: o=ty*16+i, q=tx
    #pragma unroll
    for (int i = 0; i < 16; ++i) {
        const int o = ty * 16 + i;
        const float s1 = c1_gamma[o] * rsqrtf(c1_var[o] + EPS_);
        M[((size_t)b * 64 + o) * 64 + tx] = s1 * acc[i];
    }
}

// ---------------------------------------------------------------------------
// C: fused t-recompute + conv2 + bn + relu.
// Per block: t[j,n] = relu(sum_q M[b,j,q]*att[b,q,n] + bias1[j]) into LDS,
// then out[b,o,n] = relu(s2[o]*(conv+c2_b[o]) + beta2[o]-mean2[o]*s2[o]),
// conv = sum_j c2_w[o,j]*t[j,n] + sum_c c2_w[o,64+c]*x[b,c,n].
// grid (HW/64, C/64, B), block (64,4).
// ---------------------------------------------------------------------------
__global__ __launch_bounds__(256) void k_fused_out(
        const float* __restrict__ att, const float* __restrict__ Mw,
        const float* __restrict__ c1_b, const float* __restrict__ c1_gamma,
        const float* __restrict__ c1_beta, const float* __restrict__ c1_mean,
        const float* __restrict__ c1_var,
        const float* __restrict__ x, const float* __restrict__ c2_w,
        const float* __restrict__ c2_b, const float* __restrict__ c2_gamma,
        const float* __restrict__ c2_beta, const float* __restrict__ c2_mean,
        const float* __restrict__ c2_var, float* __restrict__ out) {
    __shared__ __align__(16) float sA[64][65];  // att tile / x tiles [row][n]
    __shared__ __align__(16) float sW[64][68];  // M tile [q][j], then c2_w tiles [j][o]
    __shared__ __align__(16) float tS[64][65];  // t tile [j][n]
    const int tx = threadIdx.x, ty = threadIdx.y;
    const int n0 = blockIdx.x * 64, o0 = blockIdx.y * 64, b = blockIdx.z;

    // phase 1: t tile
    #pragma unroll
    for (int i = 0; i < 16; ++i) {
        const int r = ty * 16 + i;
        sA[r][tx] = att[((size_t)b * C8_ + r) * HW_ + n0 + tx]; // [q][n]
        sW[tx][r] = Mw[((size_t)b * 64 + r) * 64 + tx];          // [q][j]
    }
    __syncthreads();
    float acc[16];
    #pragma unroll
    for (int i = 0; i < 16; ++i) acc[i] = 0.f;
    #pragma unroll 4
    for (int q = 0; q < 64; ++q)
        FMA16(acc, sA[q][tx], &sW[q][ty * 16]);  // acc[i]: j=ty*16+i, n=tx
    #pragma unroll
    for (int i = 0; i < 16; ++i) {
        const int j = ty * 16 + i;
        const float s1 = c1_gamma[j] * rsqrtf(c1_var[j] + EPS_);
        const float bias = s1 * c1_b[j] + c1_beta[j] - c1_mean[j] * s1;
        tS[j][tx] = fmaxf(acc[i] + bias, 0.f);
    }
    __syncthreads();   // tS ready; sA/sW free to reuse

    // phase 2: conv2 over 9 input chunks (chunk 0 = tS, 1..8 = x)
    #pragma unroll
    for (int i = 0; i < 16; ++i) acc[i] = 0.f;
    for (int cch = 0; cch < 9; ++cch) {
        #pragma unroll
        for (int i = 0; i < 16; ++i) {
            const int r = ty * 16 + i;
            sW[tx][r] = c2_w[(size_t)(o0 + r) * KW2_ + cch * 64 + tx]; // [j][o]
            if (cch > 0)
                sA[r][tx] = x[((size_t)b * C_ + (cch - 1) * 64 + r) * HW_ + n0 + tx];
        }
        __syncthreads();
        const float (*src)[65] = (cch == 0) ? tS : sA;
        #pragma unroll 4
        for (int jj = 0; jj < 64; ++jj)
            FMA16(acc, src[jj][tx], &sW[jj][ty * 16]);  // acc[i]: o=o0+ty*16+i, n=tx
        __syncthreads();
    }
    #pragma unroll
    for (int i = 0; i < 16; ++i) {
        const int o = o0 + ty * 16 + i;
        const float s2 = c2_gamma[o] * rsqrtf(c2_var[o] + EPS_);
        const float v = (acc[i] + c2_b[o]) * s2 + c2_beta[o] - c2_mean[o] * s2;
        out[((size_t)b * C_ + o) * HW_ + n0 + tx] = fmaxf(v, 0.f);
    }
}

extern "C" void kernel_launch(void* const* d_in, const int* in_sizes, int n_in,
                              void* d_out, int out_size, void* d_ws, size_t ws_size,
                              hipStream_t stream) {
    const float* x        = (const float*)d_in[0];
    const float* att      = (const float*)d_in[1];
    const float* key_w    = (const float*)d_in[2];
    const float* key_b    = (const float*)d_in[3];
    const float* c1_w     = (const float*)d_in[4];
    const float* c1_b     = (const float*)d_in[5];
    const float* c1_gamma = (const float*)d_in[6];
    const float* c1_beta  = (const float*)d_in[7];
    const float* c1_mean  = (const float*)d_in[8];
    const float* c1_var   = (const float*)d_in[9];
    const float* c2_w     = (const float*)d_in[10];
    const float* c2_b     = (const float*)d_in[11];
    const float* c2_gamma = (const float*)d_in[12];
    const float* c2_beta  = (const float*)d_in[13];
    const float* c2_mean  = (const float*)d_in[14];
    const float* c2_var   = (const float*)d_in[15];
    float* out = (float*)d_out;

    // Workspace: only M (64KB floats = 256KB bytes). epart borrows the head of
    // d_out — it is fully consumed by k_softmax_M before k_fused_out
    // overwrites every element of d_out (stream-ordered).
    float* M     = (float*)d_ws;                     // B*64*64   =    65,536 f
    float* epart = out;                              // B*16*64*64 = 1,048,576 f

    dim3 blk(64, 4);
    k_key_energy<<<dim3(16, B_),              blk, 0, stream>>>(x, key_w, key_b, att, epart);
    k_softmax_M <<<dim3(B_),                  blk, 0, stream>>>(epart, c1_w, c1_gamma, c1_var, M);
    k_fused_out <<<dim3(HW_ / 64, C_ / 64, B_), blk, 0, stream>>>(
        att, M, c1_b, c1_gamma, c1_beta, c1_mean, c1_var,
        x, c2_w, c2_b, c2_gamma, c2_beta, c2_mean, c2_var, out);
}

// Round 7
// 320.157 us; speedup vs baseline: 3.1847x; 3.1847x over previous
//
#include <hip/hip_runtime.h>
#include <math.h>

#define B_   16
#define C_   512
#define C8_  64
#define HW_  4096
#define KW2_ 576   // C_ + C8_
#define EPS_ 1e-5f

typedef __attribute__((ext_vector_type(8))) short bf16x8;
typedef __attribute__((ext_vector_type(4))) float f32x4;

__device__ __forceinline__ unsigned short f2bf(float f) {
    union { float f; unsigned u; } v; v.f = f;
    unsigned r = (v.u + 0x7FFFu + ((v.u >> 16) & 1u)) >> 16;  // RNE
    return (unsigned short)r;
}

// 16-output FMA microtile: accv[i] += rowptr[i] * sv (fp32 fallback path)
#define FMA16(accv, sv, rowptr) do {                                            \
    const float4* _w = (const float4*)(rowptr);                                 \
    float4 _w0 = _w[0], _w1 = _w[1], _w2 = _w[2], _w3 = _w[3];                  \
    float _s = (sv);                                                            \
    accv[0]  += _w0.x*_s; accv[1]  += _w0.y*_s; accv[2]  += _w0.z*_s; accv[3]  += _w0.w*_s; \
    accv[4]  += _w1.x*_s; accv[5]  += _w1.y*_s; accv[6]  += _w1.z*_s; accv[7]  += _w1.w*_s; \
    accv[8]  += _w2.x*_s; accv[9]  += _w2.y*_s; accv[10] += _w2.z*_s; accv[11] += _w2.w*_s; \
    accv[12] += _w3.x*_s; accv[13] += _w3.y*_s; accv[14] += _w3.z*_s; accv[15] += _w3.w*_s; \
} while (0)

// ---------------------------------------------------------------------------
// A: fused proj_key + partial energy (fp32). grid (16,B), block (64,4).
// ---------------------------------------------------------------------------
__global__ __launch_bounds__(256) void k_key_energy(
        const float* __restrict__ x, const float* __restrict__ key_w,
        const float* __restrict__ key_b, const float* __restrict__ att,
        float* __restrict__ epart) {
    __shared__ __align__(16) float sA[64][65];
    __shared__ __align__(16) float sW[64][68];
    __shared__ __align__(16) float keyS[64][65];
    __shared__ __align__(16) float attT[64][68];
    const int tx = threadIdx.x, ty = threadIdx.y;
    const int ch = blockIdx.x, b = blockIdx.y;

    float eacc[16];
    #pragma unroll
    for (int i = 0; i < 16; ++i) eacc[i] = 0.f;

    for (int sc = 0; sc < 4; ++sc) {
        const int nb = ch * 256 + sc * 64;
        float kacc[16];
        #pragma unroll
        for (int i = 0; i < 16; ++i) kacc[i] = 0.f;

        for (int cc = 0; cc < 8; ++cc) {
            const int c0 = cc * 64;
            #pragma unroll
            for (int i = 0; i < 16; ++i) {
                const int r = ty * 16 + i;
                sA[r][tx] = x[((size_t)b * C_ + c0 + r) * HW_ + nb + tx];
                sW[tx][r] = key_w[(size_t)r * C_ + c0 + tx];
            }
            __syncthreads();
            #pragma unroll 4
            for (int jj = 0; jj < 64; ++jj)
                FMA16(kacc, sA[jj][tx], &sW[jj][ty * 16]);
            __syncthreads();
        }
        #pragma unroll
        for (int i = 0; i < 16; ++i) {
            const int r = ty * 16 + i;
            keyS[r][tx] = kacc[i] + key_b[r];
            attT[tx][r] = att[((size_t)b * C8_ + r) * HW_ + nb + tx];
        }
        __syncthreads();
        #pragma unroll 4
        for (int nn = 0; nn < 64; ++nn)
            FMA16(eacc, keyS[tx][nn], &attT[nn][ty * 16]);
        __syncthreads();
    }
    #pragma unroll
    for (int j = 0; j < 16; ++j) {
        const int q = ty * 16 + j;
        epart[((size_t)(b * 16 + ch) * 64 + q) * 64 + tx] = eacc[j];
    }
}

// ---------------------------------------------------------------------------
// B: reduce -> softmax(q) -> M[b][o][q] = s1[o]*sum_k c1_w[o,k]*attn[k,q]
// grid (B), block (64,4).
// ---------------------------------------------------------------------------
__global__ __launch_bounds__(256) void k_softmax_M(
        const float* __restrict__ epart, const float* __restrict__ c1_w,
        const float* __restrict__ c1_gamma, const float* __restrict__ c1_var,
        float* __restrict__ M) {
    __shared__ __align__(16) float eT[64][65];
    __shared__ __align__(16) float attnS[64][65];
    __shared__ __align__(16) float c1T[64][68];
    const int tx = threadIdx.x, ty = threadIdx.y;
    const int t = ty * 64 + tx;
    const int b = blockIdx.x;

    for (int idx = t; idx < 4096; idx += 256) {
        float s = 0.f;
        #pragma unroll
        for (int ch = 0; ch < 16; ++ch)
            s += epart[(size_t)(b * 16 + ch) * 4096 + idx];
        eT[idx >> 6][idx & 63] = s;
    }
    #pragma unroll
    for (int i = 0; i < 16; ++i) {
        const int oo = ty * 16 + i;
        c1T[tx][oo] = c1_w[oo * 64 + tx];
    }
    __syncthreads();

    if (t < 64) {
        const int k = t;
        float m = -1e30f;
        for (int q = 0; q < 64; ++q) m = fmaxf(m, eT[q][k]);
        float s = 0.f;
        for (int q = 0; q < 64; ++q) {
            const float p = __expf(eT[q][k] - m);
            attnS[k][q] = p;
            s += p;
        }
        const float inv = 1.f / s;
        for (int q = 0; q < 64; ++q) attnS[k][q] *= inv;
    }
    __syncthreads();

    float acc[16];
    #pragma unroll
    for (int i = 0; i < 16; ++i) acc[i] = 0.f;
    #pragma unroll 4
    for (int k = 0; k < 64; ++k)
        FMA16(acc, attnS[k][tx], &c1T[k][ty * 16]);
    #pragma unroll
    for (int i = 0; i < 16; ++i) {
        const int o = ty * 16 + i;
        const float s1 = c1_gamma[o] * rsqrtf(c1_var[o] + EPS_);
        M[((size_t)b * 64 + o) * 64 + tx] = s1 * acc[i];
    }
}

// ---------------------------------------------------------------------------
// T1: transpose-convert x -> actT[b][n][C8_+c] bf16. grid (64, 8, B), 256 thr.
// ---------------------------------------------------------------------------
__global__ __launch_bounds__(256) void k_xT(
        const float* __restrict__ x, unsigned short* __restrict__ actT) {
    __shared__ float S[64][65];
    const int t = threadIdx.x;
    const int tx = t & 63, ty = t >> 6;
    const int n0 = blockIdx.x * 64, c0 = blockIdx.y * 64, b = blockIdx.z;
    #pragma unroll
    for (int i = 0; i < 16; ++i) {
        const int r = ty * 16 + i;
        S[r][tx] = x[((size_t)(b * C_ + c0 + r)) * HW_ + n0 + tx];
    }
    __syncthreads();
    const int nl = t >> 2, seg = t & 3;
    unsigned short tmp[16];
    #pragma unroll
    for (int j = 0; j < 16; ++j) tmp[j] = f2bf(S[seg * 16 + j][nl]);
    unsigned short* dst = actT + ((size_t)(b * HW_ + n0 + nl)) * KW2_ + C8_ + c0 + seg * 16;
    *(bf16x8*)(dst)     = *(const bf16x8*)&tmp[0];
    *(bf16x8*)(dst + 8) = *(const bf16x8*)&tmp[8];
}

// ---------------------------------------------------------------------------
// T2: t[j,n] = relu(sum_q M[b,j,q]*att[b,q,n] + bias1[j]) -> actT[b][n][j] bf16
// grid (64, B), 256 thr.
// ---------------------------------------------------------------------------
__global__ __launch_bounds__(256) void k_t_bf(
        const float* __restrict__ att, const float* __restrict__ Mw,
        const float* __restrict__ c1_b, const float* __restrict__ c1_gamma,
        const float* __restrict__ c1_beta, const float* __restrict__ c1_mean,
        const float* __restrict__ c1_var, unsigned short* __restrict__ actT) {
    __shared__ __align__(16) float attS[64][65];
    __shared__ __align__(16) float MT[64][68];
    __shared__ float tS[64][65];
    const int t = threadIdx.x;
    const int tx = t & 63, ty = t >> 6;
    const int n0 = blockIdx.x * 64, b = blockIdx.y;

    #pragma unroll
    for (int i = 0; i < 16; ++i) {
        const int r = ty * 16 + i;
        attS[r][tx] = att[((size_t)b * C8_ + r) * HW_ + n0 + tx];
        MT[tx][r]   = Mw[((size_t)b * 64 + r) * 64 + tx];
    }
    __syncthreads();
    float acc[16];
    #pragma unroll
    for (int i = 0; i < 16; ++i) acc[i] = 0.f;
    #pragma unroll 4
    for (int q = 0; q < 64; ++q)
        FMA16(acc, attS[q][tx], &MT[q][ty * 16]);
    #pragma unroll
    for (int i = 0; i < 16; ++i) {
        const int j = ty * 16 + i;
        const float s1 = c1_gamma[j] * rsqrtf(c1_var[j] + EPS_);
        const float bias = s1 * c1_b[j] + c1_beta[j] - c1_mean[j] * s1;
        tS[j][tx] = fmaxf(acc[i] + bias, 0.f);
    }
    __syncthreads();
    const int nl = t >> 2, seg = t & 3;
    unsigned short tmp[16];
    #pragma unroll
    for (int j = 0; j < 16; ++j) tmp[j] = f2bf(tS[seg * 16 + j][nl]);
    unsigned short* dst = actT + ((size_t)(b * HW_ + n0 + nl)) * KW2_ + seg * 16;
    *(bf16x8*)(dst)     = *(const bf16x8*)&tmp[0];
    *(bf16x8*)(dst + 8) = *(const bf16x8*)&tmp[8];
}

// ---------------------------------------------------------------------------
// G: conv2 as bf16 MFMA GEMM. out[b,o,n] = relu((s2*W)·act + bias2)
// Block 128x128, 4 waves (2x2), wave tile 64x64 (4x4 of 16x16x32 MFMA).
// LDS: XOR-swizzled 16B blocks (kb ^ (row&7)), row stride 128B -> uniform banks.
// grid (32, 4, B), 256 thr.
// ---------------------------------------------------------------------------
__global__ __launch_bounds__(256) void k_conv2_mfma(
        const unsigned short* __restrict__ actT, const float* __restrict__ c2_w,
        const float* __restrict__ c2_b, const float* __restrict__ c2_gamma,
        const float* __restrict__ c2_beta, const float* __restrict__ c2_mean,
        const float* __restrict__ c2_var, float* __restrict__ out) {
    __shared__ __align__(16) unsigned short At[128 * 64];
    __shared__ __align__(16) unsigned short Bt[128 * 64];
    const int t = threadIdx.x;
    const int lane = t & 63, wave = t >> 6;
    const int wr = wave >> 1, wc = wave & 1;
    const int n0 = blockIdx.x * 128, o0 = blockIdx.y * 128, b = blockIdx.z;

    const int srow = t >> 1, shalf = t & 1;   // staging row 0..127, k-half 0/1
    const int oA = o0 + srow;
    const float s2A = c2_gamma[oA] * rsqrtf(c2_var[oA] + EPS_);

    f32x4 acc[4][4];
    #pragma unroll
    for (int m = 0; m < 4; ++m)
        #pragma unroll
        for (int n = 0; n < 4; ++n) acc[m][n] = (f32x4){0.f, 0.f, 0.f, 0.f};

    for (int ks = 0; ks < 9; ++ks) {
        const int k0 = ks * 64;
        {   // stage A: weights fp32 -> bf16, s2-scaled
            const float4* src = (const float4*)(c2_w + (size_t)oA * KW2_ + k0 + shalf * 32);
            unsigned short tmp[32];
            #pragma unroll
            for (int v = 0; v < 8; ++v) {
                float4 f = src[v];
                tmp[v * 4 + 0] = f2bf(f.x * s2A);
                tmp[v * 4 + 1] = f2bf(f.y * s2A);
                tmp[v * 4 + 2] = f2bf(f.z * s2A);
                tmp[v * 4 + 3] = f2bf(f.w * s2A);
            }
            #pragma unroll
            for (int v = 0; v < 4; ++v) {
                const int kb = shalf * 4 + v;
                *(bf16x8*)&At[srow * 64 + ((kb ^ (srow & 7)) << 3)] =
                    *(const bf16x8*)&tmp[v * 8];
            }
        }
        {   // stage B: actT bf16 direct copy
            const unsigned short* src =
                actT + ((size_t)(b * HW_ + n0 + srow)) * KW2_ + k0 + shalf * 32;
            #pragma unroll
            for (int v = 0; v < 4; ++v) {
                const int kb = shalf * 4 + v;
                *(bf16x8*)&Bt[srow * 64 + ((kb ^ (srow & 7)) << 3)] =
                    *(const bf16x8*)(src + v * 8);
            }
        }
        __syncthreads();
        #pragma unroll
        for (int kk = 0; kk < 2; ++kk) {
            const int g = lane >> 4, a7 = lane & 7, r15 = lane & 15;
            const int kb = kk * 4 + g;
            bf16x8 af[4], bfv[4];
            #pragma unroll
            for (int m = 0; m < 4; ++m) {
                const int row = wr * 64 + m * 16 + r15;
                af[m] = *(const bf16x8*)&At[row * 64 + ((kb ^ a7) << 3)];
            }
            #pragma unroll
            for (int n = 0; n < 4; ++n) {
                const int row = wc * 64 + n * 16 + r15;
                bfv[n] = *(const bf16x8*)&Bt[row * 64 + ((kb ^ a7) << 3)];
            }
            #pragma unroll
            for (int m = 0; m < 4; ++m)
                #pragma unroll
                for (int n = 0; n < 4; ++n)
                    acc[m][n] = __builtin_amdgcn_mfma_f32_16x16x32_bf16(
                        af[m], bfv[n], acc[m][n], 0, 0, 0);
        }
        __syncthreads();
    }
    // epilogue: D row=(lane>>4)*4+r (o), col=lane&15 (n)
    #pragma unroll
    for (int m = 0; m < 4; ++m) {
        #pragma unroll
        for (int r = 0; r < 4; ++r) {
            const int o = o0 + wr * 64 + m * 16 + (lane >> 4) * 4 + r;
            const float s2 = c2_gamma[o] * rsqrtf(c2_var[o] + EPS_);
            const float bias = s2 * (c2_b[o] - c2_mean[o]) + c2_beta[o];
            float* orow = out + ((size_t)(b * C_ + o)) * HW_ + n0 + wc * 64 + (lane & 15);
            #pragma unroll
            for (int n = 0; n < 4; ++n)
                orow[n * 16] = fmaxf(acc[m][n][r] + bias, 0.f);
        }
    }
}

// ---------------------------------------------------------------------------
// Fallback (proven round-6 path): fused t-recompute + conv2 in fp32 VALU.
// ---------------------------------------------------------------------------
__global__ __launch_bounds__(256) void k_fused_out(
        const float* __restrict__ att, const float* __restrict__ Mw,
        const float* __restrict__ c1_b, const float* __restrict__ c1_gamma,
        const float* __restrict__ c1_beta, const float* __restrict__ c1_mean,
        const float* __restrict__ c1_var,
        const float* __restrict__ x, const float* __restrict__ c2_w,
        const float* __restrict__ c2_b, const float* __restrict__ c2_gamma,
        const float* __restrict__ c2_beta, const float* __restrict__ c2_mean,
        const float* __restrict__ c2_var, float* __restrict__ out) {
    __shared__ __align__(16) float sA[64][65];
    __shared__ __align__(16) float sW[64][68];
    __shared__ __align__(16) float tS[64][65];
    const int tx = threadIdx.x, ty = threadIdx.y;
    const int n0 = blockIdx.x * 64, o0 = blockIdx.y * 64, b = blockIdx.z;

    #pragma unroll
    for (int i = 0; i < 16; ++i) {
        const int r = ty * 16 + i;
        sA[r][tx] = att[((size_t)b * C8_ + r) * HW_ + n0 + tx];
        sW[tx][r] = Mw[((size_t)b * 64 + r) * 64 + tx];
    }
    __syncthreads();
    float acc[16];
    #pragma unroll
    for (int i = 0; i < 16; ++i) acc[i] = 0.f;
    #pragma unroll 4
    for (int q = 0; q < 64; ++q)
        FMA16(acc, sA[q][tx], &sW[q][ty * 16]);
    #pragma unroll
    for (int i = 0; i < 16; ++i) {
        const int j = ty * 16 + i;
        const float s1 = c1_gamma[j] * rsqrtf(c1_var[j] + EPS_);
        const float bias = s1 * c1_b[j] + c1_beta[j] - c1_mean[j] * s1;
        tS[j][tx] = fmaxf(acc[i] + bias, 0.f);
    }
    __syncthreads();

    #pragma unroll
    for (int i = 0; i < 16; ++i) acc[i] = 0.f;
    for (int cch = 0; cch < 9; ++cch) {
        #pragma unroll
        for (int i = 0; i < 16; ++i) {
            const int r = ty * 16 + i;
            sW[tx][r] = c2_w[(size_t)(o0 + r) * KW2_ + cch * 64 + tx];
            if (cch > 0)
                sA[r][tx] = x[((size_t)b * C_ + (cch - 1) * 64 + r) * HW_ + n0 + tx];
        }
        __syncthreads();
        const float (*src)[65] = (cch == 0) ? tS : sA;
        #pragma unroll 4
        for (int jj = 0; jj < 64; ++jj)
            FMA16(acc, src[jj][tx], &sW[jj][ty * 16]);
        __syncthreads();
    }
    #pragma unroll
    for (int i = 0; i < 16; ++i) {
        const int o = o0 + ty * 16 + i;
        const float s2 = c2_gamma[o] * rsqrtf(c2_var[o] + EPS_);
        const float v = (acc[i] + c2_b[o]) * s2 + c2_beta[o] - c2_mean[o] * s2;
        out[((size_t)b * C_ + o) * HW_ + n0 + tx] = fmaxf(v, 0.f);
    }
}

extern "C" void kernel_launch(void* const* d_in, const int* in_sizes, int n_in,
                              void* d_out, int out_size, void* d_ws, size_t ws_size,
                              hipStream_t stream) {
    const float* x        = (const float*)d_in[0];
    const float* att      = (const float*)d_in[1];
    const float* key_w    = (const float*)d_in[2];
    const float* key_b    = (const float*)d_in[3];
    const float* c1_w     = (const float*)d_in[4];
    const float* c1_b     = (const float*)d_in[5];
    const float* c1_gamma = (const float*)d_in[6];
    const float* c1_beta  = (const float*)d_in[7];
    const float* c1_mean  = (const float*)d_in[8];
    const float* c1_var   = (const float*)d_in[9];
    const float* c2_w     = (const float*)d_in[10];
    const float* c2_b     = (const float*)d_in[11];
    const float* c2_gamma = (const float*)d_in[12];
    const float* c2_beta  = (const float*)d_in[13];
    const float* c2_mean  = (const float*)d_in[14];
    const float* c2_var   = (const float*)d_in[15];
    float* out = (float*)d_out;

    // ws layout: M (256 KB) | actT (B*HW*576 bf16 = 75.5 MB)
    float* M = (float*)d_ws;
    unsigned short* actT = (unsigned short*)((char*)d_ws + 262144);
    const size_t ws_needed = 262144 + (size_t)B_ * HW_ * KW2_ * 2;

    // epart borrows the head of d_out; consumed by k_softmax_M before
    // anything writes out (stream-ordered).
    float* epart = out;

    dim3 blk(64, 4);
    k_key_energy<<<dim3(16, B_), blk, 0, stream>>>(x, key_w, key_b, att, epart);
    k_softmax_M <<<dim3(B_),     blk, 0, stream>>>(epart, c1_w, c1_gamma, c1_var, M);

    if (ws_size >= ws_needed) {
        k_xT        <<<dim3(64, 8, B_), 256, 0, stream>>>(x, actT);
        k_t_bf      <<<dim3(64, B_),    256, 0, stream>>>(
            att, M, c1_b, c1_gamma, c1_beta, c1_mean, c1_var, actT);
        k_conv2_mfma<<<dim3(32, 4, B_), 256, 0, stream>>>(
            actT, c2_w, c2_b, c2_gamma, c2_beta, c2_mean, c2_var, out);
    } else {
        k_fused_out<<<dim3(HW_ / 64, C_ / 64, B_), blk, 0, stream>>>(
            att, M, c1_b, c1_gamma, c1_beta, c1_mean, c1_var,
            x, c2_w, c2_b, c2_gamma, c2_beta, c2_mean, c2_var, out);
    }
}